// Round 10
// baseline (1421.925 us; speedup 1.0000x reference)
//
#include <hip/hip_runtime.h>

#define N_PTS 32768
#define K_CB  8192
#define D_DIM 256
#define BETA  0.5f

typedef _Float16 f16;
typedef __attribute__((ext_vector_type(8))) _Float16 f16x8;
typedef __attribute__((ext_vector_type(16))) float f32x16;

#define MARGIN  2.5e-4f
#define CAPQ    16                 // per-octant candidate cap
#define NOCT    8
#define DSCALE  4096.0f
#define INV2S   (-4.8828125e-4f)   // -2/4096, exact power of two
#define CBB     16                 // codes per k_codebook block

// ---------------- ws layout (byte offsets) ----------------
#define OFF_CB   ((size_t)0)                                  // f32 [K][D]   8 MB
#define OFF_DH   (OFF_CB   + (size_t)K_CB*D_DIM*4)            // f16 delta*4096 [K][D] 4 MB
#define OFF_UH   (OFF_DH   + (size_t)K_CB*D_DIM*2)            // f16 (z-b) [N][D] 16 MB
#define OFF_CC   (OFF_UH   + (size_t)N_PTS*D_DIM*2)           // f32 ||c||^2 [K]
#define OFF_ZZ   (OFF_CC   + (size_t)K_CB*4)                  // f32 ||z||^2 [N]
#define OFF_D2   (OFF_ZZ   + (size_t)N_PTS*4)                 // f32 ||delta||^2 [K]
#define OFF_CAND (OFF_D2   + (size_t)K_CB*4)                  // u16 [N][8][CAPQ] 8 MB
#define OFF_CNT  (OFF_CAND + (size_t)N_PTS*NOCT*CAPQ*2)       // u32 [N][8]  1 MB
#define OFF_BEST (OFF_CNT  + (size_t)N_PTS*NOCT*4)            // u64 [N]
#define OFF_ACC  (OFF_BEST + (size_t)N_PTS*8)
#define WS_NEED  (OFF_ACC + 64)

// ---------------- fallback (round-1) ws layout, float offsets ----------------
#define F_CB_OFF   0
#define F_CC_OFF   (K_CB * D_DIM)
#define F_ZZ_OFF   (F_CC_OFF + K_CB)
#define F_IDX_OFF  (F_ZZ_OFF + N_PTS)
#define F_ACC_BYTE ((size_t)(F_IDX_OFF + N_PTS) * 4)

// ---------------------------------------------------------------------------
// k_codebook v2 (measured good in r9): 16 codes/block, 512 blocks.
// ---------------------------------------------------------------------------
__global__ __launch_bounds__(256) void k_codebook(
    const float* __restrict__ emb, const float* __restrict__ w,
    const float* __restrict__ bias, float* __restrict__ cb,
    float* __restrict__ cc, float* __restrict__ dd2, f16* __restrict__ dh) {
  __shared__ float esL[CBB][D_DIM];        // 16 KB
  __shared__ float wL[D_DIM][37];          // 37.9 KB (32 cols + odd pad)
  __shared__ float cbL[CBB][D_DIM + 1];    // 16.4 KB (stride 257)
  __shared__ float biasL[D_DIM];           // 1 KB
  const int tid = threadIdx.x;
  const int k0 = blockIdx.x * CBB;

#pragma unroll
  for (int r = 0; r < CBB; ++r) esL[r][tid] = emb[(size_t)(k0 + r) * D_DIM + tid];
  biasL[tid] = bias[tid];
  __syncthreads();

  float acc[CBB];
#pragma unroll
  for (int r = 0; r < CBB; ++r) acc[r] = 0.f;

  const int d = tid;
  for (int ch = 0; ch < 8; ++ch) {
    const int j0 = ch * 32;
#pragma unroll
    for (int s = 0; s < 8; ++s) {
      int idx = tid + s * 256;
      int row = idx >> 3, c4 = (idx & 7) * 4;
      float4 v = *(const float4*)&w[(size_t)row * D_DIM + j0 + c4];
      wL[row][c4 + 0] = v.x; wL[row][c4 + 1] = v.y;
      wL[row][c4 + 2] = v.z; wL[row][c4 + 3] = v.w;
    }
    __syncthreads();
#pragma unroll
    for (int jj = 0; jj < 32; jj += 4) {
      float w0 = wL[d][jj + 0], w1 = wL[d][jj + 1];
      float w2 = wL[d][jj + 2], w3 = wL[d][jj + 3];
#pragma unroll
      for (int r = 0; r < CBB; ++r) {
        float4 e = *(const float4*)&esL[r][j0 + jj];   // broadcast b128
        acc[r] = fmaf(e.x, w0, acc[r]);
        acc[r] = fmaf(e.y, w1, acc[r]);
        acc[r] = fmaf(e.z, w2, acc[r]);
        acc[r] = fmaf(e.w, w3, acc[r]);
      }
    }
    __syncthreads();
  }

  const float bd = biasL[d];
#pragma unroll
  for (int r = 0; r < CBB; ++r) {
    float a = acc[r] + bd;
    cb[(size_t)(k0 + r) * D_DIM + d] = a;
    cbL[r][d] = a;
    if (dh) dh[(size_t)(k0 + r) * D_DIM + d] = (f16)((a - bd) * DSCALE);
  }
  __syncthreads();
  if (tid < CBB) {
    float s = 0.f;
    for (int j = 0; j < D_DIM; ++j) { float v = cbL[tid][j]; s = fmaf(v, v, s); }
    cc[k0 + tid] = s;
  } else if (tid < 2 * CBB && dd2) {
    int r = tid - CBB;
    float s = 0.f;
    for (int j = 0; j < D_DIM; ++j) { float dl = cbL[r][j] - biasL[j]; s = fmaf(dl, dl, s); }
    dd2[k0 + r] = s;
  }
}

__global__ __launch_bounds__(256) void k_zz(const float* __restrict__ z,
                                            float* __restrict__ zz) {
  const int n = blockIdx.x * 256 + threadIdx.x;
  const float* zr = z + (size_t)n * D_DIM;
  float s = 0.f;
#pragma unroll 8
  for (int q = 0; q < D_DIM / 4; ++q) {
    float4 v = *(const float4*)&zr[q * 4];
    s = fmaf(v.x, v.x, s);
    s = fmaf(v.y, v.y, s);
    s = fmaf(v.z, v.z, s);
    s = fmaf(v.w, v.w, s);
  }
  zz[n] = s;
}

// uh[n][d] = f16(z[n][d] - b[d])
__global__ __launch_bounds__(256) void k_zu(const float* __restrict__ z,
                                            const float* __restrict__ bias,
                                            f16* __restrict__ uh) {
  const size_t i = (size_t)blockIdx.x * 256 + threadIdx.x;  // 8 elems/thread
  const int d0 = (int)((i * 8) & (D_DIM - 1));
  const float4* zp = (const float4*)(z + i * 8);
  float4 a = zp[0], c = zp[1];
  float4 b0 = *(const float4*)&bias[d0];
  float4 b1 = *(const float4*)&bias[d0 + 4];
  f16x8 o = {(f16)(a.x - b0.x), (f16)(a.y - b0.y), (f16)(a.z - b0.z), (f16)(a.w - b0.w),
             (f16)(c.x - b1.x), (f16)(c.y - b1.y), (f16)(c.z - b1.z), (f16)(c.w - b1.w)};
  *(f16x8*)(uh + i * 8) = o;
}

// ---------------------------------------------------------------------------
// k_main: centered f16-MFMA pass. s~(n,k) = -2 u.delta + ||delta||^2
// Grid 512 = 64 row-blocks x 8 code-octants (2 blocks/CU for overlap).
// Block 512 thr = 8 waves x 64 rows; per wave 2 resident u-sets; tile =
// 32 codes x 256 depth f16, double-buffered, XOR-swizzled (slot^ (code&7)).
// ---------------------------------------------------------------------------
__global__ __launch_bounds__(512, 4) void k_main(
    const f16* __restrict__ uh, const f16* __restrict__ dh,
    const float* __restrict__ dd2,
    unsigned int* __restrict__ cntG, unsigned short* __restrict__ candG) {
  __shared__ __align__(16) char tile[2][16384];
  __shared__ unsigned short candL[512][CAPQ];
  __shared__ unsigned int cntL[512];

  const int tid = threadIdx.x;
  const int w = tid >> 6, l = tid & 63;
  const int lc = l & 31, h = l >> 5;
  const int rb = blockIdx.x >> 3, oct = blockIdx.x & 7;
  const int n0 = rb * 512;
  const int lrowA = w * 64 + lc;
  const int lrowB = lrowA + 32;
  const int rowA = n0 + lrowA, rowB = n0 + lrowB;
  const int code0 = oct * 1024;

  cntL[tid] = 0;

  // resident u fragments: lane holds k = kc*16 + h*8 + j  (B-operand layout)
  const f16x8* uv = (const f16x8*)uh;
  f16x8 ua[16], ub[16];
#pragma unroll
  for (int kc = 0; kc < 16; ++kc) {
    ua[kc] = uv[(size_t)rowA * 32 + kc * 2 + h];
    ub[kc] = uv[(size_t)rowB * 32 + kc * 2 + h];
  }

  // staging: tile = 1024 16B-slots; slot m -> code m>>5, slot s=m&31;
  // pre-swizzled global source s^(code&7), linear LDS dest
  const f16x8* cv = (const f16x8*)dh;
  const int m0 = tid, m1 = tid + 512;
  const int cl0 = m0 >> 5, s0 = (m0 & 31) ^ (cl0 & 7);
  const int cl1 = m1 >> 5, s1 = (m1 & 31) ^ (cl1 & 7);
  const size_t base0 = (size_t)(code0 + cl0) * 32 + s0;
  const size_t base1 = (size_t)(code0 + cl1) * 32 + s1;

  {
    f16x8 a = cv[base0], b2 = cv[base1];
    *(f16x8*)(tile[0] + m0 * 16) = a;
    *(f16x8*)(tile[0] + m1 * 16) = b2;
  }
  __syncthreads();

  float runA = 3.4e38f, runB = 3.4e38f;
  const float4* d2v = (const float4*)dd2;
  int buf = 0;
  for (int t = 0; t < 32; ++t) {
    f16x8 nx0, nx1;
    if (t < 31) {  // issue next-tile loads early; land after MFMA
      nx0 = cv[base0 + (size_t)(t + 1) * 1024];
      nx1 = cv[base1 + (size_t)(t + 1) * 1024];
    }
    f32x16 accA = {0.f,0.f,0.f,0.f,0.f,0.f,0.f,0.f,0.f,0.f,0.f,0.f,0.f,0.f,0.f,0.f};
    f32x16 accB = {0.f,0.f,0.f,0.f,0.f,0.f,0.f,0.f,0.f,0.f,0.f,0.f,0.f,0.f,0.f,0.f};
    const char* cbase = tile[buf] + lc * 512;
#pragma unroll
    for (int kc = 0; kc < 16; ++kc) {
      f16x8 af = *(const f16x8*)(cbase + (((kc * 2 + h) ^ (lc & 7)) << 4));
      accA = __builtin_amdgcn_mfma_f32_32x32x16_f16(af, ua[kc], accA, 0, 0, 0);
      accB = __builtin_amdgcn_mfma_f32_32x32x16_f16(af, ub[kc], accB, 0, 0, 0);
    }

    // epilogue: s~ = fma(dot, -2^-11, dd2)   (dot = 4096 * u.delta)
    const int tb = code0 + t * 32;
    float sA[16], sB[16];
    float mA = 3.4e38f, mB = 3.4e38f;
#pragma unroll
    for (int r4 = 0; r4 < 4; ++r4) {
      float4 dq = d2v[(tb + 8 * r4 + 4 * h) >> 2];
      sA[4*r4+0] = fmaf(accA[4*r4+0], INV2S, dq.x);
      sA[4*r4+1] = fmaf(accA[4*r4+1], INV2S, dq.y);
      sA[4*r4+2] = fmaf(accA[4*r4+2], INV2S, dq.z);
      sA[4*r4+3] = fmaf(accA[4*r4+3], INV2S, dq.w);
      sB[4*r4+0] = fmaf(accB[4*r4+0], INV2S, dq.x);
      sB[4*r4+1] = fmaf(accB[4*r4+1], INV2S, dq.y);
      sB[4*r4+2] = fmaf(accB[4*r4+2], INV2S, dq.z);
      sB[4*r4+3] = fmaf(accB[4*r4+3], INV2S, dq.w);
      mA = fminf(mA, fminf(fminf(sA[4*r4+0], sA[4*r4+1]), fminf(sA[4*r4+2], sA[4*r4+3])));
      mB = fminf(mB, fminf(fminf(sB[4*r4+0], sB[4*r4+1]), fminf(sB[4*r4+2], sB[4*r4+3])));
    }
    // lanes l and l^32 hold the same rows (different code offsets) -> merge
    mA = fminf(mA, __shfl_xor(mA, 32));
    mB = fminf(mB, __shfl_xor(mB, 32));
    runA = fminf(runA, mA);
    runB = fminf(runB, mB);
    const float thA = runA + MARGIN, thB = runB + MARGIN;
#pragma unroll
    for (int r = 0; r < 16; ++r) {
      const int code = tb + 8 * (r >> 2) + 4 * h + (r & 3);
      if (sA[r] < thA) {
        unsigned int p = atomicAdd(&cntL[lrowA], 1u);
        if (p < CAPQ) candL[lrowA][p] = (unsigned short)code;
      }
      if (sB[r] < thB) {
        unsigned int p = atomicAdd(&cntL[lrowB], 1u);
        if (p < CAPQ) candL[lrowB][p] = (unsigned short)code;
      }
    }
    if (t < 31) {
      *(f16x8*)(tile[buf ^ 1] + m0 * 16) = nx0;
      *(f16x8*)(tile[buf ^ 1] + m1 * 16) = nx1;
    }
    __syncthreads();
    buf ^= 1;
  }

  // writeout: thread tid owns row n0+tid
  unsigned int c = cntL[tid];
  unsigned int cw = (c > CAPQ) ? 0xFFFFu : c;
  cntG[((size_t)(n0 + tid)) * NOCT + oct] = cw;
  unsigned int nc = (cw == 0xFFFFu) ? 0u : cw;
  for (unsigned int j = 0; j < nc; ++j)
    candG[(((size_t)(n0 + tid)) * NOCT + oct) * CAPQ + j] = candL[tid][j];
}

// exact fp32 distance, bit-replicating the round-1 (reference-matching) formula
__device__ inline unsigned long long exact_key(const float* __restrict__ zr,
                                               const float* __restrict__ cb,
                                               float zzn, const float* __restrict__ cc,
                                               int code) {
  float acc = 0.f;
  const float4* cr = (const float4*)&cb[(size_t)code * D_DIM];
  const float4* z4p = (const float4*)zr;
#pragma unroll 8
  for (int u = 0; u < D_DIM / 4; ++u) {
    float4 c4 = cr[u], z4 = z4p[u];
    acc = fmaf(z4.x, c4.x, acc);
    acc = fmaf(z4.y, c4.y, acc);
    acc = fmaf(z4.z, c4.z, acc);
    acc = fmaf(z4.w, c4.w, acc);
  }
  float t = zzn + cc[code];
  float dd = fmaf(-2.f, acc, t);
  return (((unsigned long long)__float_as_uint(dd)) << 32) | (unsigned int)code;
}

// one wave per row; refine candidate lists (or full-scan on sentinel)
__global__ __launch_bounds__(256) void k_refine(
    const float* __restrict__ z, const float* __restrict__ cb,
    const float* __restrict__ zz, const float* __restrict__ cc,
    const unsigned int* __restrict__ cntG, const unsigned short* __restrict__ candG,
    unsigned long long* __restrict__ best) {
  __shared__ float zls[4][D_DIM];
  const int tid = threadIdx.x;
  const int v = tid >> 6, l = tid & 63;
  const int n = blockIdx.x * 4 + v;
  *(float4*)&zls[v][l * 4] = *(const float4*)&z[(size_t)n * D_DIM + l * 4];
  __syncthreads();

  unsigned int cq[NOCT];
  bool full = false;
#pragma unroll
  for (int i = 0; i < NOCT; ++i) {
    cq[i] = cntG[(size_t)n * NOCT + i];
    full |= (cq[i] == 0xFFFFu);
  }
  const float zzn = zz[n];
  unsigned long long key = ~0ull;

  if (!full) {
    unsigned int off[NOCT];
    unsigned int tot = 0;
#pragma unroll
    for (int i = 0; i < NOCT; ++i) { off[i] = tot; tot += cq[i]; }
    for (unsigned int ci = l; ci < tot; ci += 64) {
      int oc = 0;
#pragma unroll
      for (int i = 1; i < NOCT; ++i) oc = (ci >= off[i]) ? i : oc;
      unsigned int j = ci - off[oc];
      int code = candG[((size_t)n * NOCT + oc) * CAPQ + j];
      unsigned long long k2 = exact_key(zls[v], cb, zzn, cc, code);
      key = key < k2 ? key : k2;
    }
  } else {
    for (int code = l; code < K_CB; code += 64) {
      unsigned long long k2 = exact_key(zls[v], cb, zzn, cc, code);
      key = key < k2 ? key : k2;
    }
  }
#pragma unroll
  for (int off2 = 1; off2 < 64; off2 <<= 1) {
    unsigned long long o = __shfl_xor(key, off2);
    key = key < o ? key : o;
  }
  if (l == 0) best[n] = key;
}

// ---------------------------------------------------------------------------
// round-1 exact argmin kernel (fallback path when ws too small)
// ---------------------------------------------------------------------------
#define BN  64
#define BKC 128
#define DC  32
#define LDP (DC + 4)
__global__ __launch_bounds__(256) void k_argmin(
    const float* __restrict__ z, const float* __restrict__ cb,
    const float* __restrict__ zz, const float* __restrict__ cc,
    int* __restrict__ out_idx) {
  __shared__ float zs[BN][LDP];
  __shared__ float cs[BKC][LDP];
  __shared__ float red_d[BN][16];
  __shared__ int   red_k[BN][16];
  const int tid = threadIdx.x;
  const int tn = tid & 15, tk = tid >> 4;
  const int n0 = blockIdx.x * BN;
  float zzv[4];
#pragma unroll
  for (int i = 0; i < 4; ++i) zzv[i] = zz[n0 + tn + 16 * i];
  float best[4]; int bidx[4];
#pragma unroll
  for (int i = 0; i < 4; ++i) { best[i] = 3.4e38f; bidx[i] = 0; }
  for (int kt = 0; kt < K_CB / BKC; ++kt) {
    float acc[4][8];
#pragma unroll
    for (int i = 0; i < 4; ++i)
#pragma unroll
      for (int j = 0; j < 8; ++j) acc[i][j] = 0.f;
    for (int ch = 0; ch < D_DIM / DC; ++ch) {
      __syncthreads();
#pragma unroll
      for (int s = 0; s < 2; ++s) {
        int f = tid + 256 * s, r = f >> 3, c4 = f & 7;
        *(float4*)&zs[r][c4 * 4] =
            *(const float4*)&z[(size_t)(n0 + r) * D_DIM + ch * DC + c4 * 4];
      }
#pragma unroll
      for (int s = 0; s < 4; ++s) {
        int f = tid + 256 * s, r = f >> 3, c4 = f & 7;
        *(float4*)&cs[r][c4 * 4] =
            *(const float4*)&cb[(size_t)(kt * BKC + r) * D_DIM + ch * DC + c4 * 4];
      }
      __syncthreads();
#pragma unroll
      for (int qq = 0; qq < DC / 4; ++qq) {
        float4 zr[4], cr[8];
#pragma unroll
        for (int i = 0; i < 4; ++i) zr[i] = *(const float4*)&zs[tn + 16 * i][4 * qq];
#pragma unroll
        for (int j = 0; j < 8; ++j) cr[j] = *(const float4*)&cs[tk + 16 * j][4 * qq];
#pragma unroll
        for (int i = 0; i < 4; ++i)
#pragma unroll
          for (int j = 0; j < 8; ++j) {
            acc[i][j] = fmaf(zr[i].x, cr[j].x, acc[i][j]);
            acc[i][j] = fmaf(zr[i].y, cr[j].y, acc[i][j]);
            acc[i][j] = fmaf(zr[i].z, cr[j].z, acc[i][j]);
            acc[i][j] = fmaf(zr[i].w, cr[j].w, acc[i][j]);
          }
      }
    }
#pragma unroll
    for (int j = 0; j < 8; ++j) {
      const int k = kt * BKC + tk + 16 * j;
      const float cck = cc[k];
#pragma unroll
      for (int i = 0; i < 4; ++i) {
        float t = zzv[i] + cck;
        float dd = fmaf(-2.f, acc[i][j], t);
        if (dd < best[i]) { best[i] = dd; bidx[i] = k; }
      }
    }
  }
#pragma unroll
  for (int i = 0; i < 4; ++i) {
    red_d[tn + 16 * i][tk] = best[i];
    red_k[tn + 16 * i][tk] = bidx[i];
  }
  __syncthreads();
  if (tid < BN) {
    float bd = red_d[tid][0]; int bk = red_k[tid][0];
#pragma unroll
    for (int t2 = 1; t2 < 16; ++t2) {
      float dd = red_d[tid][t2]; int kk = red_k[tid][t2];
      if (dd < bd || (dd == bd && kk < bk)) { bd = dd; bk = kk; }
    }
    out_idx[n0 + tid] = bk;
  }
}

// ---------------------------------------------------------------------------
// gather + straight-through out + loss partials
// ---------------------------------------------------------------------------
template <int MODE>
__global__ __launch_bounds__(256) void k_gather(
    const float* __restrict__ z, const float* __restrict__ cb,
    const void* __restrict__ idx_src, float* __restrict__ out,
    double* __restrict__ accum) {
  const int tid = threadIdx.x;
  const int lane = tid & 63, wv = tid >> 6;
  const int base = blockIdx.x * 64 + wv * 16;
  double lsum = 0.0;
  for (int r = 0; r < 16; ++r) {
    const int n = base + r;
    int k;
    if (MODE == 0) k = ((const int*)idx_src)[n];
    else k = (int)(((const unsigned long long*)idx_src)[n] & 8191ull);
    float4 c4 = *(const float4*)&cb[(size_t)k * D_DIM + lane * 4];
    float4 z4 = *(const float4*)&z[(size_t)n * D_DIM + lane * 4];
    float e0 = c4.x - z4.x, e1 = c4.y - z4.y, e2 = c4.z - z4.z, e3 = c4.w - z4.w;
    lsum += (double)e0 * e0 + (double)e1 * e1 + (double)e2 * e2 + (double)e3 * e3;
    float4 o;
    o.x = z4.x + e0; o.y = z4.y + e1; o.z = z4.z + e2; o.w = z4.w + e3;
    *(float4*)&out[(size_t)n * D_DIM + lane * 4] = o;
    if (lane == 0) out[(size_t)N_PTS * D_DIM + n] = (float)k;
  }
#pragma unroll
  for (int off = 32; off > 0; off >>= 1) lsum += __shfl_down(lsum, off);
  __shared__ double wsum[4];
  if (lane == 0) wsum[wv] = lsum;
  __syncthreads();
  if (tid == 0) atomicAdd(accum, wsum[0] + wsum[1] + wsum[2] + wsum[3]);
}

__global__ void k_loss(const double* __restrict__ accum, float* __restrict__ out) {
  float m = (float)(*accum / (double)((size_t)N_PTS * D_DIM));
  out[(size_t)N_PTS * D_DIM + N_PTS] = BETA * m + m;
}

extern "C" void kernel_launch(void* const* d_in, const int* in_sizes, int n_in,
                              void* d_out, int out_size, void* d_ws, size_t ws_size,
                              hipStream_t stream) {
  const float* z   = (const float*)d_in[0];
  const float* emb = (const float*)d_in[1];
  const float* w   = (const float*)d_in[2];
  const float* b   = (const float*)d_in[3];
  float* out = (float*)d_out;
  char* ws = (char*)d_ws;

  if (ws_size >= WS_NEED) {
    float* cb  = (float*)(ws + OFF_CB);
    f16*   dh  = (f16*)(ws + OFF_DH);
    f16*   uh  = (f16*)(ws + OFF_UH);
    float* cc  = (float*)(ws + OFF_CC);
    float* zz  = (float*)(ws + OFF_ZZ);
    float* dd2 = (float*)(ws + OFF_D2);
    unsigned short* candG = (unsigned short*)(ws + OFF_CAND);
    unsigned int*   cntG  = (unsigned int*)(ws + OFF_CNT);
    unsigned long long* best = (unsigned long long*)(ws + OFF_BEST);
    double* accum = (double*)(ws + OFF_ACC);

    hipMemsetAsync(accum, 0, 8, stream);

    k_codebook<<<K_CB / CBB, 256, 0, stream>>>(emb, w, b, cb, cc, dd2, dh);
    k_zz<<<N_PTS / 256, 256, 0, stream>>>(z, zz);
    k_zu<<<(N_PTS * D_DIM) / (8 * 256), 256, 0, stream>>>(z, b, uh);
    k_main<<<512, 512, 0, stream>>>(uh, dh, dd2, cntG, candG);
    k_refine<<<N_PTS / 4, 256, 0, stream>>>(z, cb, zz, cc, cntG, candG, best);
    k_gather<1><<<N_PTS / 64, 256, 0, stream>>>(z, cb, best, out, accum);
    k_loss<<<1, 1, 0, stream>>>(accum, out);
  } else {
    float* ws_f = (float*)d_ws;
    float* cb = ws_f + F_CB_OFF;
    float* cc = ws_f + F_CC_OFF;
    float* zz = ws_f + F_ZZ_OFF;
    int*   idx = (int*)(ws_f + F_IDX_OFF);
    double* accum = (double*)((char*)d_ws + F_ACC_BYTE);
    hipMemsetAsync(accum, 0, sizeof(double), stream);
    k_codebook<<<K_CB / CBB, 256, 0, stream>>>(emb, w, b, cb, cc, (float*)nullptr, (f16*)nullptr);
    k_zz<<<N_PTS / 256, 256, 0, stream>>>(z, zz);
    k_argmin<<<N_PTS / BN, 256, 0, stream>>>(z, cb, zz, cc, idx);
    k_gather<0><<<N_PTS / 64, 256, 0, stream>>>(z, cb, idx, out, accum);
    k_loss<<<1, 1, 0, stream>>>(accum, out);
  }
}

// Round 11
// 1071.353 us; speedup vs baseline: 1.3272x; 1.3272x over previous
//
#include <hip/hip_runtime.h>

#define N_PTS 32768
#define K_CB  8192
#define D_DIM 256
#define BETA  0.5f

typedef _Float16 f16;
typedef __attribute__((ext_vector_type(8))) _Float16 f16x8;
typedef __attribute__((ext_vector_type(16))) float f32x16;

#define MARGIN  2.5e-4f
#define CAPQ    16                 // per-octant candidate cap
#define NOCT    8
#define DSCALE  4096.0f
#define INV2S   (-4.8828125e-4f)   // -2/4096, exact power of two
#define CBB     16                 // codes per k_codebook block

// ---------------- ws layout (byte offsets) ----------------
#define OFF_CB   ((size_t)0)                                  // f32 [K][D]   8 MB
#define OFF_DH   (OFF_CB   + (size_t)K_CB*D_DIM*4)            // f16 delta*4096 [K][D] 4 MB
#define OFF_UH   (OFF_DH   + (size_t)K_CB*D_DIM*2)            // f16 (z-b) [N][D] 16 MB
#define OFF_CC   (OFF_UH   + (size_t)N_PTS*D_DIM*2)           // f32 ||c||^2 [K]
#define OFF_ZZ   (OFF_CC   + (size_t)K_CB*4)                  // f32 ||z||^2 [N]
#define OFF_D2   (OFF_ZZ   + (size_t)N_PTS*4)                 // f32 ||delta||^2 [K]
#define OFF_CAND (OFF_D2   + (size_t)K_CB*4)                  // u16 [N][8][CAPQ] 8 MB
#define OFF_CNT  (OFF_CAND + (size_t)N_PTS*NOCT*CAPQ*2)       // u32 [N][8]  1 MB
#define OFF_BEST (OFF_CNT  + (size_t)N_PTS*NOCT*4)            // u64 [N]
#define OFF_RMIN (OFF_BEST + (size_t)N_PTS*8)                 // u32 [N] 128 KB
#define OFF_ACC  (OFF_RMIN + (size_t)N_PTS*4)
#define WS_NEED  (OFF_ACC + 64)

// ---------------- fallback (round-1) ws layout, float offsets ----------------
#define F_CB_OFF   0
#define F_CC_OFF   (K_CB * D_DIM)
#define F_ZZ_OFF   (F_CC_OFF + K_CB)
#define F_IDX_OFF  (F_ZZ_OFF + N_PTS)
#define F_ACC_BYTE ((size_t)(F_IDX_OFF + N_PTS) * 4)

// order-preserving float<->uint for atomicMin over signed floats
__device__ inline unsigned int encf(float f) {
  unsigned int u = __float_as_uint(f);
  return (u & 0x80000000u) ? ~u : (u | 0x80000000u);
}
__device__ inline float decf(unsigned int e) {
  unsigned int u = (e & 0x80000000u) ? (e & 0x7fffffffu) : ~e;
  return __uint_as_float(u);
}

// ---------------------------------------------------------------------------
// k_codebook v2 (measured good in r9): 16 codes/block, 512 blocks.
// ---------------------------------------------------------------------------
__global__ __launch_bounds__(256) void k_codebook(
    const float* __restrict__ emb, const float* __restrict__ w,
    const float* __restrict__ bias, float* __restrict__ cb,
    float* __restrict__ cc, float* __restrict__ dd2, f16* __restrict__ dh) {
  __shared__ float esL[CBB][D_DIM];        // 16 KB
  __shared__ float wL[D_DIM][37];          // 37.9 KB (32 cols + odd pad)
  __shared__ float cbL[CBB][D_DIM + 1];    // 16.4 KB (stride 257)
  __shared__ float biasL[D_DIM];           // 1 KB
  const int tid = threadIdx.x;
  const int k0 = blockIdx.x * CBB;

#pragma unroll
  for (int r = 0; r < CBB; ++r) esL[r][tid] = emb[(size_t)(k0 + r) * D_DIM + tid];
  biasL[tid] = bias[tid];
  __syncthreads();

  float acc[CBB];
#pragma unroll
  for (int r = 0; r < CBB; ++r) acc[r] = 0.f;

  const int d = tid;
  for (int ch = 0; ch < 8; ++ch) {
    const int j0 = ch * 32;
#pragma unroll
    for (int s = 0; s < 8; ++s) {
      int idx = tid + s * 256;
      int row = idx >> 3, c4 = (idx & 7) * 4;
      float4 v = *(const float4*)&w[(size_t)row * D_DIM + j0 + c4];
      wL[row][c4 + 0] = v.x; wL[row][c4 + 1] = v.y;
      wL[row][c4 + 2] = v.z; wL[row][c4 + 3] = v.w;
    }
    __syncthreads();
#pragma unroll
    for (int jj = 0; jj < 32; jj += 4) {
      float w0 = wL[d][jj + 0], w1 = wL[d][jj + 1];
      float w2 = wL[d][jj + 2], w3 = wL[d][jj + 3];
#pragma unroll
      for (int r = 0; r < CBB; ++r) {
        float4 e = *(const float4*)&esL[r][j0 + jj];   // broadcast b128
        acc[r] = fmaf(e.x, w0, acc[r]);
        acc[r] = fmaf(e.y, w1, acc[r]);
        acc[r] = fmaf(e.z, w2, acc[r]);
        acc[r] = fmaf(e.w, w3, acc[r]);
      }
    }
    __syncthreads();
  }

  const float bd = biasL[d];
#pragma unroll
  for (int r = 0; r < CBB; ++r) {
    float a = acc[r] + bd;
    cb[(size_t)(k0 + r) * D_DIM + d] = a;
    cbL[r][d] = a;
    if (dh) dh[(size_t)(k0 + r) * D_DIM + d] = (f16)((a - bd) * DSCALE);
  }
  __syncthreads();
  if (tid < CBB) {
    float s = 0.f;
    for (int j = 0; j < D_DIM; ++j) { float v = cbL[tid][j]; s = fmaf(v, v, s); }
    cc[k0 + tid] = s;
  } else if (tid < 2 * CBB && dd2) {
    int r = tid - CBB;
    float s = 0.f;
    for (int j = 0; j < D_DIM; ++j) { float dl = cbL[r][j] - biasL[j]; s = fmaf(dl, dl, s); }
    dd2[k0 + r] = s;
  }
}

__global__ __launch_bounds__(256) void k_zz(const float* __restrict__ z,
                                            float* __restrict__ zz) {
  const int n = blockIdx.x * 256 + threadIdx.x;
  const float* zr = z + (size_t)n * D_DIM;
  float s = 0.f;
#pragma unroll 8
  for (int q = 0; q < D_DIM / 4; ++q) {
    float4 v = *(const float4*)&zr[q * 4];
    s = fmaf(v.x, v.x, s);
    s = fmaf(v.y, v.y, s);
    s = fmaf(v.z, v.z, s);
    s = fmaf(v.w, v.w, s);
  }
  zz[n] = s;
}

// uh[n][d] = f16(z[n][d] - b[d])
__global__ __launch_bounds__(256) void k_zu(const float* __restrict__ z,
                                            const float* __restrict__ bias,
                                            f16* __restrict__ uh) {
  const size_t i = (size_t)blockIdx.x * 256 + threadIdx.x;  // 8 elems/thread
  const int d0 = (int)((i * 8) & (D_DIM - 1));
  const float4* zp = (const float4*)(z + i * 8);
  float4 a = zp[0], c = zp[1];
  float4 b0 = *(const float4*)&bias[d0];
  float4 b1 = *(const float4*)&bias[d0 + 4];
  f16x8 o = {(f16)(a.x - b0.x), (f16)(a.y - b0.y), (f16)(a.z - b0.z), (f16)(a.w - b0.w),
             (f16)(c.x - b1.x), (f16)(c.y - b1.y), (f16)(c.z - b1.z), (f16)(c.w - b1.w)};
  *(f16x8*)(uh + i * 8) = o;
}

// ---------------------------------------------------------------------------
// k_main: centered f16-MFMA pass. s~(n,k) = -2 u.delta + ||delta||^2
// Grid 512 = 64 row-blocks x 8 octants; 2 blocks/CU (LDS 32KB, VGPR<=128).
// Threshold tightened via cross-block shared rowmin (atomicMin, encf order-map):
// thr = min(local_run, global_estimate) + MARGIN  — keeps the flagged set a
// superset of the exact argmin (estimate >= true s~ min) while making flag
// counts region-size-invariant. Candidates go straight to global lists.
// ---------------------------------------------------------------------------
__global__ __launch_bounds__(512, 4) void k_main(
    const f16* __restrict__ uh, const f16* __restrict__ dh,
    const float* __restrict__ dd2, unsigned int* __restrict__ rmin,
    unsigned int* __restrict__ cntG, unsigned short* __restrict__ candG) {
  __shared__ __align__(16) char tile[2][16384];

  const int tid = threadIdx.x;
  const int w = tid >> 6, l = tid & 63;
  const int lc = l & 31, h = l >> 5;
  const int rb = blockIdx.x >> 3, oct = blockIdx.x & 7;
  const int n0 = rb * 512;
  const int rowA = n0 + w * 64 + lc;
  const int rowB = rowA + 32;
  const int code0 = oct * 1024;

  // resident u fragments: lane holds k = kc*16 + h*8 + j  (B-operand layout)
  const f16x8* uv = (const f16x8*)uh;
  f16x8 ua[16], ub[16];
#pragma unroll
  for (int kc = 0; kc < 16; ++kc) {
    ua[kc] = uv[(size_t)rowA * 32 + kc * 2 + h];
    ub[kc] = uv[(size_t)rowB * 32 + kc * 2 + h];
  }

  // staging: tile = 1024 16B-slots; slot m -> code m>>5, slot s=m&31;
  // pre-swizzled global source s^(code&7), linear LDS dest
  const f16x8* cv = (const f16x8*)dh;
  const int m0 = tid, m1 = tid + 512;
  const int cl0 = m0 >> 5, s0 = (m0 & 31) ^ (cl0 & 7);
  const int cl1 = m1 >> 5, s1 = (m1 & 31) ^ (cl1 & 7);
  const size_t base0 = (size_t)(code0 + cl0) * 32 + s0;
  const size_t base1 = (size_t)(code0 + cl1) * 32 + s1;

  {
    f16x8 a = cv[base0], b2 = cv[base1];
    *(f16x8*)(tile[0] + m0 * 16) = a;
    *(f16x8*)(tile[0] + m1 * 16) = b2;
  }
  __syncthreads();

  float runA = 3.4e38f, runB = 3.4e38f;
  const float4* d2v = (const float4*)dd2;
  int buf = 0;
  for (int t = 0; t < 32; ++t) {
    f16x8 nx0, nx1;
    if (t < 31) {  // issue next-tile loads early; land after MFMA
      nx0 = cv[base0 + (size_t)(t + 1) * 1024];
      nx1 = cv[base1 + (size_t)(t + 1) * 1024];
    }
    f32x16 accA = {0.f,0.f,0.f,0.f,0.f,0.f,0.f,0.f,0.f,0.f,0.f,0.f,0.f,0.f,0.f,0.f};
    f32x16 accB = {0.f,0.f,0.f,0.f,0.f,0.f,0.f,0.f,0.f,0.f,0.f,0.f,0.f,0.f,0.f,0.f};
    const char* cbase = tile[buf] + lc * 512;
#pragma unroll
    for (int kc = 0; kc < 16; ++kc) {
      f16x8 af = *(const f16x8*)(cbase + (((kc * 2 + h) ^ (lc & 7)) << 4));
      accA = __builtin_amdgcn_mfma_f32_32x32x16_f16(af, ua[kc], accA, 0, 0, 0);
      accB = __builtin_amdgcn_mfma_f32_32x32x16_f16(af, ub[kc], accB, 0, 0, 0);
    }

    // epilogue: s~ = fma(dot, -2^-11, dd2)   (dot = 4096 * u.delta)
    const int tb = code0 + t * 32;
    float sA[16], sB[16];
    float mA = 3.4e38f, mB = 3.4e38f;
#pragma unroll
    for (int r4 = 0; r4 < 4; ++r4) {
      float4 dq = d2v[(tb + 8 * r4 + 4 * h) >> 2];
      sA[4*r4+0] = fmaf(accA[4*r4+0], INV2S, dq.x);
      sA[4*r4+1] = fmaf(accA[4*r4+1], INV2S, dq.y);
      sA[4*r4+2] = fmaf(accA[4*r4+2], INV2S, dq.z);
      sA[4*r4+3] = fmaf(accA[4*r4+3], INV2S, dq.w);
      sB[4*r4+0] = fmaf(accB[4*r4+0], INV2S, dq.x);
      sB[4*r4+1] = fmaf(accB[4*r4+1], INV2S, dq.y);
      sB[4*r4+2] = fmaf(accB[4*r4+2], INV2S, dq.z);
      sB[4*r4+3] = fmaf(accB[4*r4+3], INV2S, dq.w);
      mA = fminf(mA, fminf(fminf(sA[4*r4+0], sA[4*r4+1]), fminf(sA[4*r4+2], sA[4*r4+3])));
      mB = fminf(mB, fminf(fminf(sB[4*r4+0], sB[4*r4+1]), fminf(sB[4*r4+2], sB[4*r4+3])));
    }
    // lanes l and l^32 hold the same rows (different code offsets) -> merge
    mA = fminf(mA, __shfl_xor(mA, 32));
    mB = fminf(mB, __shfl_xor(mB, 32));
    runA = fminf(runA, mA);
    runB = fminf(runB, mB);

    // cross-block min sharing (global estimate >= true min -> superset safe)
    float gA = decf(rmin[rowA]);
    float gB = decf(rmin[rowB]);
    if (h == 0) {
      if (runA < gA) atomicMin(&rmin[rowA], encf(runA));
      if (runB < gB) atomicMin(&rmin[rowB], encf(runB));
    }
    const float thA = fminf(runA, gA) + MARGIN;
    const float thB = fminf(runB, gB) + MARGIN;
#pragma unroll
    for (int r = 0; r < 16; ++r) {
      const int code = tb + 8 * (r >> 2) + 4 * h + (r & 3);
      if (sA[r] < thA) {
        unsigned int p = atomicAdd(&cntG[(size_t)rowA * NOCT + oct], 1u);
        if (p < CAPQ) candG[((size_t)rowA * NOCT + oct) * CAPQ + p] = (unsigned short)code;
      }
      if (sB[r] < thB) {
        unsigned int p = atomicAdd(&cntG[(size_t)rowB * NOCT + oct], 1u);
        if (p < CAPQ) candG[((size_t)rowB * NOCT + oct) * CAPQ + p] = (unsigned short)code;
      }
    }
    if (t < 31) {
      *(f16x8*)(tile[buf ^ 1] + m0 * 16) = nx0;
      *(f16x8*)(tile[buf ^ 1] + m1 * 16) = nx1;
    }
    __syncthreads();
    buf ^= 1;
  }
}

// exact fp32 distance, bit-replicating the round-1 (reference-matching) formula
__device__ inline unsigned long long exact_key(const float* __restrict__ zr,
                                               const float* __restrict__ cb,
                                               float zzn, const float* __restrict__ cc,
                                               int code) {
  float acc = 0.f;
  const float4* cr = (const float4*)&cb[(size_t)code * D_DIM];
  const float4* z4p = (const float4*)zr;
#pragma unroll 8
  for (int u = 0; u < D_DIM / 4; ++u) {
    float4 c4 = cr[u], z4 = z4p[u];
    acc = fmaf(z4.x, c4.x, acc);
    acc = fmaf(z4.y, c4.y, acc);
    acc = fmaf(z4.z, c4.z, acc);
    acc = fmaf(z4.w, c4.w, acc);
  }
  float t = zzn + cc[code];
  float dd = fmaf(-2.f, acc, t);
  return (((unsigned long long)__float_as_uint(dd)) << 32) | (unsigned int)code;
}

// one wave per row; refine lists; per-octant 1024-code scan on overflow
__global__ __launch_bounds__(256) void k_refine(
    const float* __restrict__ z, const float* __restrict__ cb,
    const float* __restrict__ zz, const float* __restrict__ cc,
    const unsigned int* __restrict__ cntG, const unsigned short* __restrict__ candG,
    unsigned long long* __restrict__ best) {
  __shared__ float zls[4][D_DIM];
  const int tid = threadIdx.x;
  const int v = tid >> 6, l = tid & 63;
  const int n = blockIdx.x * 4 + v;
  *(float4*)&zls[v][l * 4] = *(const float4*)&z[(size_t)n * D_DIM + l * 4];
  __syncthreads();

  unsigned int cq[NOCT];
  unsigned int ov = 0;  // overflowed-octant bitmask
#pragma unroll
  for (int i = 0; i < NOCT; ++i) {
    unsigned int c = cntG[(size_t)n * NOCT + i];
    if (c > CAPQ) { ov |= (1u << i); cq[i] = 0; }
    else cq[i] = c;
  }
  const float zzn = zz[n];
  unsigned long long key = ~0ull;

  // list path
  {
    unsigned int off[NOCT];
    unsigned int tot = 0;
#pragma unroll
    for (int i = 0; i < NOCT; ++i) { off[i] = tot; tot += cq[i]; }
    for (unsigned int ci = l; ci < tot; ci += 64) {
      int oc = 0;
#pragma unroll
      for (int i = 1; i < NOCT; ++i) oc = (ci >= off[i]) ? i : oc;
      unsigned int j = ci - off[oc];
      int code = candG[((size_t)n * NOCT + oc) * CAPQ + j];
      unsigned long long k2 = exact_key(zls[v], cb, zzn, cc, code);
      key = key < k2 ? key : k2;
    }
  }
  // overflow path: exact scan of just the overflowed octant(s)
  while (ov) {
    int oc = __ffs(ov) - 1;
    ov &= ov - 1;
    for (int code = oc * 1024 + l; code < (oc + 1) * 1024; code += 64) {
      unsigned long long k2 = exact_key(zls[v], cb, zzn, cc, code);
      key = key < k2 ? key : k2;
    }
  }
#pragma unroll
  for (int off2 = 1; off2 < 64; off2 <<= 1) {
    unsigned long long o = __shfl_xor(key, off2);
    key = key < o ? key : o;
  }
  if (l == 0) best[n] = key;
}

// ---------------------------------------------------------------------------
// round-1 exact argmin kernel (fallback path when ws too small)
// ---------------------------------------------------------------------------
#define BN  64
#define BKC 128
#define DC  32
#define LDP (DC + 4)
__global__ __launch_bounds__(256) void k_argmin(
    const float* __restrict__ z, const float* __restrict__ cb,
    const float* __restrict__ zz, const float* __restrict__ cc,
    int* __restrict__ out_idx) {
  __shared__ float zs[BN][LDP];
  __shared__ float cs[BKC][LDP];
  __shared__ float red_d[BN][16];
  __shared__ int   red_k[BN][16];
  const int tid = threadIdx.x;
  const int tn = tid & 15, tk = tid >> 4;
  const int n0 = blockIdx.x * BN;
  float zzv[4];
#pragma unroll
  for (int i = 0; i < 4; ++i) zzv[i] = zz[n0 + tn + 16 * i];
  float best[4]; int bidx[4];
#pragma unroll
  for (int i = 0; i < 4; ++i) { best[i] = 3.4e38f; bidx[i] = 0; }
  for (int kt = 0; kt < K_CB / BKC; ++kt) {
    float acc[4][8];
#pragma unroll
    for (int i = 0; i < 4; ++i)
#pragma unroll
      for (int j = 0; j < 8; ++j) acc[i][j] = 0.f;
    for (int ch = 0; ch < D_DIM / DC; ++ch) {
      __syncthreads();
#pragma unroll
      for (int s = 0; s < 2; ++s) {
        int f = tid + 256 * s, r = f >> 3, c4 = f & 7;
        *(float4*)&zs[r][c4 * 4] =
            *(const float4*)&z[(size_t)(n0 + r) * D_DIM + ch * DC + c4 * 4];
      }
#pragma unroll
      for (int s = 0; s < 4; ++s) {
        int f = tid + 256 * s, r = f >> 3, c4 = f & 7;
        *(float4*)&cs[r][c4 * 4] =
            *(const float4*)&cb[(size_t)(kt * BKC + r) * D_DIM + ch * DC + c4 * 4];
      }
      __syncthreads();
#pragma unroll
      for (int qq = 0; qq < DC / 4; ++qq) {
        float4 zr[4], cr[8];
#pragma unroll
        for (int i = 0; i < 4; ++i) zr[i] = *(const float4*)&zs[tn + 16 * i][4 * qq];
#pragma unroll
        for (int j = 0; j < 8; ++j) cr[j] = *(const float4*)&cs[tk + 16 * j][4 * qq];
#pragma unroll
        for (int i = 0; i < 4; ++i)
#pragma unroll
          for (int j = 0; j < 8; ++j) {
            acc[i][j] = fmaf(zr[i].x, cr[j].x, acc[i][j]);
            acc[i][j] = fmaf(zr[i].y, cr[j].y, acc[i][j]);
            acc[i][j] = fmaf(zr[i].z, cr[j].z, acc[i][j]);
            acc[i][j] = fmaf(zr[i].w, cr[j].w, acc[i][j]);
          }
      }
    }
#pragma unroll
    for (int j = 0; j < 8; ++j) {
      const int k = kt * BKC + tk + 16 * j;
      const float cck = cc[k];
#pragma unroll
      for (int i = 0; i < 4; ++i) {
        float t = zzv[i] + cck;
        float dd = fmaf(-2.f, acc[i][j], t);
        if (dd < best[i]) { best[i] = dd; bidx[i] = k; }
      }
    }
  }
#pragma unroll
  for (int i = 0; i < 4; ++i) {
    red_d[tn + 16 * i][tk] = best[i];
    red_k[tn + 16 * i][tk] = bidx[i];
  }
  __syncthreads();
  if (tid < BN) {
    float bd = red_d[tid][0]; int bk = red_k[tid][0];
#pragma unroll
    for (int t2 = 1; t2 < 16; ++t2) {
      float dd = red_d[tid][t2]; int kk = red_k[tid][t2];
      if (dd < bd || (dd == bd && kk < bk)) { bd = dd; bk = kk; }
    }
    out_idx[n0 + tid] = bk;
  }
}

// ---------------------------------------------------------------------------
// gather + straight-through out + loss partials
// ---------------------------------------------------------------------------
template <int MODE>
__global__ __launch_bounds__(256) void k_gather(
    const float* __restrict__ z, const float* __restrict__ cb,
    const void* __restrict__ idx_src, float* __restrict__ out,
    double* __restrict__ accum) {
  const int tid = threadIdx.x;
  const int lane = tid & 63, wv = tid >> 6;
  const int base = blockIdx.x * 64 + wv * 16;
  double lsum = 0.0;
  for (int r = 0; r < 16; ++r) {
    const int n = base + r;
    int k;
    if (MODE == 0) k = ((const int*)idx_src)[n];
    else k = (int)(((const unsigned long long*)idx_src)[n] & 8191ull);
    float4 c4 = *(const float4*)&cb[(size_t)k * D_DIM + lane * 4];
    float4 z4 = *(const float4*)&z[(size_t)n * D_DIM + lane * 4];
    float e0 = c4.x - z4.x, e1 = c4.y - z4.y, e2 = c4.z - z4.z, e3 = c4.w - z4.w;
    lsum += (double)e0 * e0 + (double)e1 * e1 + (double)e2 * e2 + (double)e3 * e3;
    float4 o;
    o.x = z4.x + e0; o.y = z4.y + e1; o.z = z4.z + e2; o.w = z4.w + e3;
    *(float4*)&out[(size_t)n * D_DIM + lane * 4] = o;
    if (lane == 0) out[(size_t)N_PTS * D_DIM + n] = (float)k;
  }
#pragma unroll
  for (int off = 32; off > 0; off >>= 1) lsum += __shfl_down(lsum, off);
  __shared__ double wsum[4];
  if (lane == 0) wsum[wv] = lsum;
  __syncthreads();
  if (tid == 0) atomicAdd(accum, wsum[0] + wsum[1] + wsum[2] + wsum[3]);
}

__global__ void k_loss(const double* __restrict__ accum, float* __restrict__ out) {
  float m = (float)(*accum / (double)((size_t)N_PTS * D_DIM));
  out[(size_t)N_PTS * D_DIM + N_PTS] = BETA * m + m;
}

extern "C" void kernel_launch(void* const* d_in, const int* in_sizes, int n_in,
                              void* d_out, int out_size, void* d_ws, size_t ws_size,
                              hipStream_t stream) {
  const float* z   = (const float*)d_in[0];
  const float* emb = (const float*)d_in[1];
  const float* w   = (const float*)d_in[2];
  const float* b   = (const float*)d_in[3];
  float* out = (float*)d_out;
  char* ws = (char*)d_ws;

  if (ws_size >= WS_NEED) {
    float* cb  = (float*)(ws + OFF_CB);
    f16*   dh  = (f16*)(ws + OFF_DH);
    f16*   uh  = (f16*)(ws + OFF_UH);
    float* cc  = (float*)(ws + OFF_CC);
    float* zz  = (float*)(ws + OFF_ZZ);
    float* dd2 = (float*)(ws + OFF_D2);
    unsigned short* candG = (unsigned short*)(ws + OFF_CAND);
    unsigned int*   cntG  = (unsigned int*)(ws + OFF_CNT);
    unsigned long long* best = (unsigned long long*)(ws + OFF_BEST);
    unsigned int* rmin = (unsigned int*)(ws + OFF_RMIN);
    double* accum = (double*)(ws + OFF_ACC);

    hipMemsetAsync(accum, 0, 8, stream);
    hipMemsetAsync(cntG, 0, (size_t)N_PTS * NOCT * 4, stream);
    hipMemsetAsync(rmin, 0xFF, (size_t)N_PTS * 4, stream);

    k_codebook<<<K_CB / CBB, 256, 0, stream>>>(emb, w, b, cb, cc, dd2, dh);
    k_zz<<<N_PTS / 256, 256, 0, stream>>>(z, zz);
    k_zu<<<(N_PTS * D_DIM) / (8 * 256), 256, 0, stream>>>(z, b, uh);
    k_main<<<512, 512, 0, stream>>>(uh, dh, dd2, rmin, cntG, candG);
    k_refine<<<N_PTS / 4, 256, 0, stream>>>(z, cb, zz, cc, cntG, candG, best);
    k_gather<1><<<N_PTS / 64, 256, 0, stream>>>(z, cb, best, out, accum);
    k_loss<<<1, 1, 0, stream>>>(accum, out);
  } else {
    float* ws_f = (float*)d_ws;
    float* cb = ws_f + F_CB_OFF;
    float* cc = ws_f + F_CC_OFF;
    float* zz = ws_f + F_ZZ_OFF;
    int*   idx = (int*)(ws_f + F_IDX_OFF);
    double* accum = (double*)((char*)d_ws + F_ACC_BYTE);
    hipMemsetAsync(accum, 0, sizeof(double), stream);
    k_codebook<<<K_CB / CBB, 256, 0, stream>>>(emb, w, b, cb, cc, (float*)nullptr, (f16*)nullptr);
    k_zz<<<N_PTS / 256, 256, 0, stream>>>(z, zz);
    k_argmin<<<N_PTS / BN, 256, 0, stream>>>(z, cb, zz, cc, idx);
    k_gather<0><<<N_PTS / 64, 256, 0, stream>>>(z, cb, idx, out, accum);
    k_loss<<<1, 1, 0, stream>>>(accum, out);
  }
}